// Round 1
// baseline (3129.740 us; speedup 1.0000x reference)
//
#include <hip/hip_runtime.h>
#include <hip/hip_bf16.h>

#define HID 128
#define LDSW 136          // padded LDS row stride in bf16 elems (272 B -> 2-way bank alias only)
#define N_NODES_MAX 100000

typedef __attribute__((ext_vector_type(8))) short bf16x8;
typedef __attribute__((ext_vector_type(4))) short s16x4;
typedef __attribute__((ext_vector_type(4))) float f32x4;

// Static device accumulator: avoids dependence on ws_size. Zeroed every call.
__device__ float g_agg[(size_t)N_NODES_MAX * HID];

__device__ __forceinline__ short f2bf(float f) {
    unsigned u = __builtin_bit_cast(unsigned, f);
    unsigned r = (u + 0x7fffu + ((u >> 16) & 1u)) >> 16;   // RNE
    return (short)r;
}

__global__ __launch_bounds__(256) void zero_agg(int n4) {
    int i = blockIdx.x * 256 + threadIdx.x;
    if (i < n4) ((float4*)g_agg)[i] = make_float4(0.f, 0.f, 0.f, 0.f);
}

// One edge per 32 lanes; lane handles a float4 (h = lane*4 .. +3).
__global__ __launch_bounds__(256) void scatter_kernel(
    const float* __restrict__ x, const int* __restrict__ ei,
    const float* __restrict__ ew, const float* __restrict__ w_edge,
    const float* __restrict__ b_edge, int nEdges)
{
    int t = blockIdx.x * 256 + threadIdx.x;
    int e = t >> 5;
    int lane = t & 31;
    if (e >= nEdges) return;
    int src = ei[e];
    int dst = ei[nEdges + e];
    float w = ew[e];
    float4 xv = ((const float4*)(x + (size_t)src * HID))[lane];
    float4 wv = ((const float4*)w_edge)[lane];
    float4 bv = ((const float4*)b_edge)[lane];
    float4 v;
    v.x = xv.x + w * wv.x + bv.x;
    v.y = xv.y + w * wv.y + bv.y;
    v.z = xv.z + w * wv.z + bv.z;
    v.w = xv.w + w * wv.w + bv.w;
    float* ap = g_agg + (size_t)dst * HID + lane * 4;
    unsafeAtomicAdd(ap + 0, v.x);
    unsafeAtomicAdd(ap + 1, v.y);
    unsafeAtomicAdd(ap + 2, v.z);
    unsafeAtomicAdd(ap + 3, v.w);
}

// Fused: A = agg + (1+eps)*x ; H1 = relu(A@W1^T + b1) ; out = H1@W2^T + b2
// Block: 256 threads = 4 waves, 64 node-rows; wave w owns rows [16w, 16w+16).
__global__ __launch_bounds__(256) void mlp_kernel(
    const float* __restrict__ x,
    const float* __restrict__ w1, const float* __restrict__ b1,
    const float* __restrict__ w2, const float* __restrict__ b2,
    float* __restrict__ out, int nNodes)
{
    __shared__ __align__(16) short Ws[HID * LDSW];   // 34816 B: W1 then W2 (bf16)
    __shared__ __align__(16) short As[64 * LDSW];    // 17408 B: A tile, then H1

    const int tid = threadIdx.x;
    const int lane = tid & 63;
    const int wave = tid >> 6;
    const int node0 = blockIdx.x * 64;
    const int l15 = lane & 15;
    const int quad = lane >> 4;
    const int mrow = wave * 16;

    // Load A tile: agg + x (EPS=0). 64 rows x 32 float4 = 2048 chunks, 8 iters.
    for (int it = 0; it < 8; ++it) {
        int idx = it * 256 + tid;
        int r = idx >> 5, c4 = idx & 31;
        int node = node0 + r;
        float4 v = make_float4(0.f, 0.f, 0.f, 0.f);
        if (node < nNodes) {
            float4 a = ((const float4*)(g_agg + (size_t)node * HID))[c4];
            float4 xv = ((const float4*)(x + (size_t)node * HID))[c4];
            v.x = a.x + xv.x; v.y = a.y + xv.y; v.z = a.z + xv.z; v.w = a.w + xv.w;
        }
        s16x4 pk = { f2bf(v.x), f2bf(v.y), f2bf(v.z), f2bf(v.w) };
        *(s16x4*)(As + r * LDSW + c4 * 4) = pk;
    }
    // Load W1 (fp32 global -> bf16 LDS). 128 rows x 32 float4 = 4096, 16 iters.
    for (int it = 0; it < 16; ++it) {
        int idx = it * 256 + tid;
        int r = idx >> 5, c4 = idx & 31;
        float4 w = ((const float4*)(w1 + r * HID))[c4];
        s16x4 pk = { f2bf(w.x), f2bf(w.y), f2bf(w.z), f2bf(w.w) };
        *(s16x4*)(Ws + r * LDSW + c4 * 4) = pk;
    }
    __syncthreads();

    // GEMM1: each wave: 1 m-tile x 8 n-tiles, K = 4 x 32.
    bf16x8 afrag[4];
    for (int k = 0; k < 4; ++k)
        afrag[k] = *(const bf16x8*)(As + (mrow + l15) * LDSW + k * 32 + quad * 8);
    f32x4 acc[8];
    for (int nt = 0; nt < 8; ++nt) acc[nt] = (f32x4){0.f, 0.f, 0.f, 0.f};
    for (int nt = 0; nt < 8; ++nt)
        for (int k = 0; k < 4; ++k) {
            bf16x8 bfrag = *(const bf16x8*)(Ws + (nt * 16 + l15) * LDSW + k * 32 + quad * 8);
            acc[nt] = __builtin_amdgcn_mfma_f32_16x16x32_bf16(afrag[k], bfrag, acc[nt], 0, 0, 0);
        }
    __syncthreads();   // all waves done reading As (frags cached) and Ws(W1)

    // H1 = relu(acc + b1) -> As (own rows only; C/D: col=l15, row=quad*4+r)
    for (int nt = 0; nt < 8; ++nt) {
        int col = nt * 16 + l15;
        float bb = b1[col];
        for (int r = 0; r < 4; ++r) {
            float h = acc[nt][r] + bb;
            h = h > 0.f ? h : 0.f;
            As[(mrow + quad * 4 + r) * LDSW + col] = f2bf(h);
        }
    }
    // Load W2 over Ws.
    for (int it = 0; it < 16; ++it) {
        int idx = it * 256 + tid;
        int r = idx >> 5, c4 = idx & 31;
        float4 w = ((const float4*)(w2 + r * HID))[c4];
        s16x4 pk = { f2bf(w.x), f2bf(w.y), f2bf(w.z), f2bf(w.w) };
        *(s16x4*)(Ws + r * LDSW + c4 * 4) = pk;
    }
    __syncthreads();

    // GEMM2
    for (int k = 0; k < 4; ++k)
        afrag[k] = *(const bf16x8*)(As + (mrow + l15) * LDSW + k * 32 + quad * 8);
    f32x4 acc2[8];
    for (int nt = 0; nt < 8; ++nt) acc2[nt] = (f32x4){0.f, 0.f, 0.f, 0.f};
    for (int nt = 0; nt < 8; ++nt)
        for (int k = 0; k < 4; ++k) {
            bf16x8 bfrag = *(const bf16x8*)(Ws + (nt * 16 + l15) * LDSW + k * 32 + quad * 8);
            acc2[nt] = __builtin_amdgcn_mfma_f32_16x16x32_bf16(afrag[k], bfrag, acc2[nt], 0, 0, 0);
        }

    // Epilogue: out = acc2 + b2 (fp32 global)
    for (int nt = 0; nt < 8; ++nt) {
        int col = nt * 16 + l15;
        float bb = b2[col];
        for (int r = 0; r < 4; ++r) {
            int node = node0 + mrow + quad * 4 + r;
            if (node < nNodes)
                out[(size_t)node * HID + col] = acc2[nt][r] + bb;
        }
    }
}

extern "C" void kernel_launch(void* const* d_in, const int* in_sizes, int n_in,
                              void* d_out, int out_size, void* d_ws, size_t ws_size,
                              hipStream_t stream) {
    const float* x      = (const float*)d_in[0];
    const int*   ei     = (const int*)d_in[1];
    const float* ew     = (const float*)d_in[2];
    const float* w_edge = (const float*)d_in[3];
    const float* b_edge = (const float*)d_in[4];
    const float* w1     = (const float*)d_in[5];
    const float* b1     = (const float*)d_in[6];
    const float* w2     = (const float*)d_in[7];
    const float* b2     = (const float*)d_in[8];
    float* out = (float*)d_out;

    int nNodes = in_sizes[0] / HID;     // 100000
    int nEdges = in_sizes[2];           // 1600000

    int n4 = nNodes * (HID / 4);
    zero_agg<<<(n4 + 255) / 256, 256, 0, stream>>>(n4);

    int scatterThreads = nEdges * 32;
    scatter_kernel<<<(scatterThreads + 255) / 256, 256, 0, stream>>>(
        x, ei, ew, w_edge, b_edge, nEdges);

    mlp_kernel<<<(nNodes + 63) / 64, 256, 0, stream>>>(
        x, w1, b1, w2, b2, out, nNodes);
}

// Round 2
// 458.888 us; speedup vs baseline: 6.8203x; 6.8203x over previous
//
#include <hip/hip_runtime.h>
#include <hip/hip_bf16.h>

#define HID 128
#define LDSW 136          // padded LDS row stride in bf16 elems
#define NMAX 100000
#define EMAX 1600000

typedef __attribute__((ext_vector_type(8))) short bf16x8;
typedef __attribute__((ext_vector_type(4))) short s16x4;
typedef __attribute__((ext_vector_type(4))) float f32x4;

// Static device scratch (persistent; fully rewritten every call).
__device__ int   g_cnt[NMAX + 1];
__device__ int   g_off[NMAX + 1];
__device__ int   g_cur[NMAX + 1];
__device__ int   g_incl[NMAX + 512];
__device__ int   g_bsum[256];
__device__ int   g_boff[256];
__device__ int2  g_srcw[EMAX];                 // packed {src, bitcast(w)} sorted by dst
__device__ short g_A[(size_t)NMAX * HID];      // bf16 A = agg + (1+eps)*x
__device__ short g_xb[(size_t)NMAX * HID];     // bf16 copy of x for gathers

__device__ __forceinline__ short f2bf(float f) {
    unsigned u = __builtin_bit_cast(unsigned, f);
    unsigned r = (u + 0x7fffu + ((u >> 16) & 1u)) >> 16;   // RNE
    return (short)r;
}
__device__ __forceinline__ float bf2f(short s) {
    unsigned u = ((unsigned)(unsigned short)s) << 16;
    return __builtin_bit_cast(float, u);
}

__global__ __launch_bounds__(256) void zero_cnt(int n) {
    int i = blockIdx.x * 256 + threadIdx.x;
    if (i < n) g_cnt[i] = 0;
}

// x fp32 -> bf16 (4 elems/thread)
__global__ __launch_bounds__(256) void xcast_kernel(const float* __restrict__ x, int n4) {
    int i = blockIdx.x * 256 + threadIdx.x;
    if (i >= n4) return;
    float4 v = ((const float4*)x)[i];
    s16x4 pk = { f2bf(v.x), f2bf(v.y), f2bf(v.z), f2bf(v.w) };
    *(s16x4*)(g_xb + (size_t)i * 4) = pk;
}

__global__ __launch_bounds__(256) void hist_kernel(const int* __restrict__ ei, int nEdges) {
    int e = blockIdx.x * 256 + threadIdx.x;
    if (e < nEdges) atomicAdd(&g_cnt[ei[nEdges + e]], 1);
}

// Block-local inclusive scan of counts (512/block)
__global__ __launch_bounds__(512) void scan1_kernel(int n) {
    __shared__ int s[512];
    int tid = threadIdx.x;
    int i = blockIdx.x * 512 + tid;
    int v = (i < n) ? g_cnt[i] : 0;
    s[tid] = v;
    __syncthreads();
    for (int d = 1; d < 512; d <<= 1) {
        int t = (tid >= d) ? s[tid - d] : 0;
        __syncthreads();
        s[tid] += t;
        __syncthreads();
    }
    if (i < n) g_incl[i] = s[tid];
    if (tid == 511) g_bsum[blockIdx.x] = s[511];
}

// Scan of block sums (single block)
__global__ __launch_bounds__(256) void scan2_kernel(int nb) {
    __shared__ int s[256];
    int tid = threadIdx.x;
    int v = (tid < nb) ? g_bsum[tid] : 0;
    s[tid] = v;
    __syncthreads();
    for (int d = 1; d < 256; d <<= 1) {
        int t = (tid >= d) ? s[tid - d] : 0;
        __syncthreads();
        s[tid] += t;
        __syncthreads();
    }
    g_boff[tid] = s[tid] - v;   // exclusive
}

// off[i] = exclusive scan; cur[i] = off[i]; off[n]=nEdges
__global__ __launch_bounds__(256) void scan3_kernel(int n, int nEdges) {
    int i = blockIdx.x * 256 + threadIdx.x;
    if (i > n) return;
    int off;
    if (i == n) off = nEdges;
    else        off = g_boff[i >> 9] + g_incl[i] - g_cnt[i];
    g_off[i] = off;
    g_cur[i] = off;
}

__global__ __launch_bounds__(256) void fill_kernel(
    const int* __restrict__ ei, const float* __restrict__ ew, int nEdges) {
    int e = blockIdx.x * 256 + threadIdx.x;
    if (e >= nEdges) return;
    int d = ei[nEdges + e];
    int pos = atomicAdd(&g_cur[d], 1);
    int2 sw;
    sw.x = ei[e];
    sw.y = __float_as_int(ew[e]);
    g_srcw[pos] = sw;
}

// One wave per node; lanes split into 2 half-waves each handling one edge/iter.
// li = lane&31 owns features [li*4, li*4+4).
__global__ __launch_bounds__(256) void gather_kernel(
    const float* __restrict__ x, const float* __restrict__ w_edge,
    const float* __restrict__ b_edge, int nNodes)
{
    int node = blockIdx.x * 4 + (threadIdx.x >> 6);
    if (node >= nNodes) return;
    int lane = threadIdx.x & 63;
    int sub = lane >> 5, li = lane & 31;

    int start = g_off[node];
    int end   = g_off[node + 1];
    float4 we = ((const float4*)w_edge)[li];
    float4 be = ((const float4*)b_edge)[li];

    float a0 = 0.f, a1 = 0.f, a2 = 0.f, a3 = 0.f;
    for (int e = start + sub; e < end; e += 2) {
        int2 sw = g_srcw[e];
        float w = __int_as_float(sw.y);
        s16x4 xb = *(const s16x4*)(g_xb + (size_t)sw.x * HID + li * 4);
        a0 += bf2f(xb[0]) + w * we.x + be.x;
        a1 += bf2f(xb[1]) + w * we.y + be.y;
        a2 += bf2f(xb[2]) + w * we.z + be.z;
        a3 += bf2f(xb[3]) + w * we.w + be.w;
    }
    // combine the two half-wave partials
    a0 += __shfl_xor(a0, 32, 64);
    a1 += __shfl_xor(a1, 32, 64);
    a2 += __shfl_xor(a2, 32, 64);
    a3 += __shfl_xor(a3, 32, 64);

    if (sub == 0) {
        float4 xv = ((const float4*)(x + (size_t)node * HID))[li];  // fp32 self term
        a0 += xv.x; a1 += xv.y; a2 += xv.z; a3 += xv.w;
        s16x4 pk = { f2bf(a0), f2bf(a1), f2bf(a2), f2bf(a3) };
        *(s16x4*)(g_A + (size_t)node * HID + li * 4) = pk;
    }
}

// MLP: H1 = relu(A@W1^T + b1); out = H1@W2^T + b2. A is bf16 in g_A.
__global__ __launch_bounds__(256) void mlp_kernel(
    const float* __restrict__ w1, const float* __restrict__ b1,
    const float* __restrict__ w2, const float* __restrict__ b2,
    float* __restrict__ out, int nNodes)
{
    __shared__ __align__(16) short Ws[HID * LDSW];
    __shared__ __align__(16) short As[64 * LDSW];

    const int tid = threadIdx.x;
    const int lane = tid & 63;
    const int wave = tid >> 6;
    const int node0 = blockIdx.x * 64;
    const int l15 = lane & 15;
    const int quad = lane >> 4;
    const int mrow = wave * 16;

    // A tile: 64 rows x 32 s16x4 chunks
    for (int it = 0; it < 8; ++it) {
        int idx = it * 256 + tid;
        int r = idx >> 5, c = idx & 31;
        int node = node0 + r;
        s16x4 v = { 0, 0, 0, 0 };
        if (node < nNodes) v = *(const s16x4*)(g_A + (size_t)node * HID + c * 4);
        *(s16x4*)(As + r * LDSW + c * 4) = v;
    }
    // W1 fp32 -> bf16 LDS
    for (int it = 0; it < 16; ++it) {
        int idx = it * 256 + tid;
        int r = idx >> 5, c4 = idx & 31;
        float4 w = ((const float4*)(w1 + r * HID))[c4];
        s16x4 pk = { f2bf(w.x), f2bf(w.y), f2bf(w.z), f2bf(w.w) };
        *(s16x4*)(Ws + r * LDSW + c4 * 4) = pk;
    }
    __syncthreads();

    bf16x8 afrag[4];
    for (int k = 0; k < 4; ++k)
        afrag[k] = *(const bf16x8*)(As + (mrow + l15) * LDSW + k * 32 + quad * 8);
    f32x4 acc[8];
    for (int nt = 0; nt < 8; ++nt) acc[nt] = (f32x4){0.f, 0.f, 0.f, 0.f};
    for (int nt = 0; nt < 8; ++nt)
        for (int k = 0; k < 4; ++k) {
            bf16x8 bfrag = *(const bf16x8*)(Ws + (nt * 16 + l15) * LDSW + k * 32 + quad * 8);
            acc[nt] = __builtin_amdgcn_mfma_f32_16x16x32_bf16(afrag[k], bfrag, acc[nt], 0, 0, 0);
        }
    __syncthreads();

    for (int nt = 0; nt < 8; ++nt) {
        int col = nt * 16 + l15;
        float bb = b1[col];
        for (int r = 0; r < 4; ++r) {
            float h = acc[nt][r] + bb;
            h = h > 0.f ? h : 0.f;
            As[(mrow + quad * 4 + r) * LDSW + col] = f2bf(h);
        }
    }
    for (int it = 0; it < 16; ++it) {
        int idx = it * 256 + tid;
        int r = idx >> 5, c4 = idx & 31;
        float4 w = ((const float4*)(w2 + r * HID))[c4];
        s16x4 pk = { f2bf(w.x), f2bf(w.y), f2bf(w.z), f2bf(w.w) };
        *(s16x4*)(Ws + r * LDSW + c4 * 4) = pk;
    }
    __syncthreads();

    for (int k = 0; k < 4; ++k)
        afrag[k] = *(const bf16x8*)(As + (mrow + l15) * LDSW + k * 32 + quad * 8);
    f32x4 acc2[8];
    for (int nt = 0; nt < 8; ++nt) acc2[nt] = (f32x4){0.f, 0.f, 0.f, 0.f};
    for (int nt = 0; nt < 8; ++nt)
        for (int k = 0; k < 4; ++k) {
            bf16x8 bfrag = *(const bf16x8*)(Ws + (nt * 16 + l15) * LDSW + k * 32 + quad * 8);
            acc2[nt] = __builtin_amdgcn_mfma_f32_16x16x32_bf16(afrag[k], bfrag, acc2[nt], 0, 0, 0);
        }

    for (int nt = 0; nt < 8; ++nt) {
        int col = nt * 16 + l15;
        float bb = b2[col];
        for (int r = 0; r < 4; ++r) {
            int node = node0 + mrow + quad * 4 + r;
            if (node < nNodes)
                out[(size_t)node * HID + col] = acc2[nt][r] + bb;
        }
    }
}

extern "C" void kernel_launch(void* const* d_in, const int* in_sizes, int n_in,
                              void* d_out, int out_size, void* d_ws, size_t ws_size,
                              hipStream_t stream) {
    const float* x      = (const float*)d_in[0];
    const int*   ei     = (const int*)d_in[1];
    const float* ew     = (const float*)d_in[2];
    const float* w_edge = (const float*)d_in[3];
    const float* b_edge = (const float*)d_in[4];
    const float* w1     = (const float*)d_in[5];
    const float* b1     = (const float*)d_in[6];
    const float* w2     = (const float*)d_in[7];
    const float* b2     = (const float*)d_in[8];
    float* out = (float*)d_out;

    int nNodes = in_sizes[0] / HID;     // 100000
    int nEdges = in_sizes[2];           // 1600000

    zero_cnt<<<(nNodes + 1 + 255) / 256, 256, 0, stream>>>(nNodes + 1);

    int n4 = nNodes * (HID / 4);
    xcast_kernel<<<(n4 + 255) / 256, 256, 0, stream>>>(x, n4);

    hist_kernel<<<(nEdges + 255) / 256, 256, 0, stream>>>(ei, nEdges);

    int nb = (nNodes + 511) / 512;
    scan1_kernel<<<nb, 512, 0, stream>>>(nNodes);
    scan2_kernel<<<1, 256, 0, stream>>>(nb);
    scan3_kernel<<<(nNodes + 1 + 255) / 256, 256, 0, stream>>>(nNodes, nEdges);

    fill_kernel<<<(nEdges + 255) / 256, 256, 0, stream>>>(ei, ew, nEdges);

    gather_kernel<<<(nNodes + 3) / 4, 256, 0, stream>>>(x, w_edge, b_edge, nNodes);

    mlp_kernel<<<(nNodes + 63) / 64, 256, 0, stream>>>(w1, b1, w2, b2, out, nNodes);
}